// Round 2
// baseline (215.287 us; speedup 1.0000x reference)
//
#include <hip/hip_runtime.h>
#include <hip/hip_bf16.h>

#define N_NODES 100000
#define D_FEAT 64
#define CAP 64          // slots per dst node; in-deg ~ 1+Poisson(16), P(>63) ~ 1e-14
#define NB 196          // coarse buckets of 512 nodes: 196*512 = 100352 >= n
#define CB_CAP 10200    // per-coarse-bucket record capacity (mean 8673, +16 sigma)
#define PT 512          // partition threads per block
#define EPT 7           // edges register-cached per thread; chunk = EPT*PT = 3584
#define NBD 4           // dst sub-blocks per bucket in bin (parallelism)

typedef unsigned int uint;
typedef unsigned short ushort;

// fp32 -> bf16 round-to-nearest-even
__device__ __forceinline__ uint f2bf(float f) {
    uint u = __float_as_uint(f);
    return (u + 0x7fffu + ((u >> 16) & 1u)) >> 16;
}

// ========== pass 1: coarse partition of edges by dst>>9 and src>>9 =========
// Single-read: each thread caches its <=EPT edges in registers (statically
// indexed under full unroll), histograms from registers, reserves one
// contiguous run per (block,bucket), then replays from registers.
__global__ __launch_bounds__(PT) void
partition_kernel(const int* __restrict__ src, const int* __restrict__ dst,
                 int* __restrict__ dstCur, int* __restrict__ srcCur,
                 uint* __restrict__ dstrec, ushort* __restrict__ srcrec,
                 int nE) {
    __shared__ int hd[NB], hs[NB], bd[NB], bs[NB];
    const int t = threadIdx.x;
    for (int i = t; i < NB; i += PT) { hd[i] = 0; hs[i] = 0; }
    __syncthreads();
    const int beg = blockIdx.x * (EPT * PT);
    int se[EPT], de[EPT];
#pragma unroll
    for (int k = 0; k < EPT; ++k) {
        int e = beg + t + k * PT;
        int s = 0, d = 0;
        if (e < nE) { s = src[e]; d = dst[e]; }   // coalesced
        se[k] = s; de[k] = d;
        if (e < nE) {
            atomicAdd(&hd[d >> 9], 1);
            atomicAdd(&hs[s >> 9], 1);
        }
    }
    __syncthreads();
    for (int i = t; i < NB; i += PT) {
        bd[i] = atomicAdd(&dstCur[i], hd[i]);
        bs[i] = atomicAdd(&srcCur[i], hs[i]);
        hd[i] = 0; hs[i] = 0;
    }
    __syncthreads();
#pragma unroll
    for (int k = 0; k < EPT; ++k) {
        int e = beg + t + k * PT;
        if (e < nE) {
            int d = de[k], s = se[k];
            int b = d >> 9;
            int p = bd[b] + atomicAdd(&hd[b], 1);
            if (p < CB_CAP)
                dstrec[(size_t)b * CB_CAP + p] = ((uint)(d & 511) << 17) | (uint)s;  // s < 2^17
            int b2 = s >> 9;
            int p2 = bs[b2] + atomicAdd(&hs[b2], 1);
            if (p2 < CB_CAP)
                srcrec[(size_t)b2 * CB_CAP + p2] = (ushort)(s & 511);
        }
    }
}

// ========== pass 2: fused bin + prescale ===================================
// Blocks 0..NBD*NB-1: fine-bin dst records -> edge_src, slot from GLOBAL
//   atomicAdd(cursor[node]) (cursor pre-zeroed).  NBD sub-blocks per bucket
//   -> 980 blocks (3.8/CU) of independent latency chains, vs 392 before.
//   edge_src writes stay within the bucket's 128 KB window (L2-local).
// Blocks NBD*NB..: deg_out histogram in LDS, then directly emit prescaled
//   bf16 rows xb[row] = bf16(rsqrt(deg_out)*feat[row]); deg_out never
//   touches global memory.
__global__ __launch_bounds__(256) void
bin_kernel(const ushort* __restrict__ srcrec, const int* __restrict__ srcCur,
           const uint* __restrict__ dstrec, const int* __restrict__ dstCur,
           int* __restrict__ cursor, int* __restrict__ edge_src,
           const float* __restrict__ feat, uint2* __restrict__ xb, int n) {
    __shared__ int lc[512];
    const int t = threadIdx.x;
    if ((int)blockIdx.x < NBD * NB) {
        const int b    = blockIdx.x >> 2;          // bucket (NBD == 4)
        const int j    = blockIdx.x & (NBD - 1);   // sub-block
        const int base = b << 9;
        const int cnt  = min(dstCur[b], CB_CAP);
        const int q    = (cnt + NBD - 1) / NBD;
        const int lo   = j * q;
        const int hi   = min(lo + q, cnt);
        const uint* rec = dstrec + (size_t)b * CB_CAP;
#pragma unroll 4
        for (int i = lo + t; i < hi; i += 256) {   // independent iterations -> MLP
            uint r = rec[i];
            int dl = r >> 17;
            int s  = r & 0x1FFFF;
            int p = atomicAdd(&cursor[base + dl], 1);
            if (p < CAP) edge_src[(size_t)(base + dl) * CAP + p] = s;
        }
    } else {
        const int b = blockIdx.x - NBD * NB;
        const int base = b << 9;
        for (int i = t; i < 512; i += 256) lc[i] = 0;
        __syncthreads();
        int cnt = min(srcCur[b], CB_CAP);
        const ushort* rec = srcrec + (size_t)b * CB_CAP;
        for (int i = t; i < cnt; i += 256) atomicAdd(&lc[rec[i]], 1);
        __syncthreads();
        // prescale this bucket's rows; include pad row n (zeros) when in range.
        const int rows = min(512, n + 1 - base);
        const int d4 = t & 15;
        for (int r = t >> 4; r < rows; r += 256 / 16) {
            const int row = base + r;
            uint2 o;
            if (row == n) {
                o.x = 0u; o.y = 0u;
            } else {
                float w = rsqrtf((float)max(lc[r], 1));
                float4 v = ((const float4*)feat)[(size_t)row * 16 + d4];
                o.x = f2bf(w * v.x) | (f2bf(w * v.y) << 16);
                o.y = f2bf(w * v.z) | (f2bf(w * v.w) << 16);
            }
            xb[(size_t)row * 16 + d4] = o;
        }
    }
}

// ========== pass 3: gather (body 32 / tail 16 / tail 8) ====================
// One wave per dst row; WAVE-UNIFORM loop (shfl source lanes must stay active).
// Avg cnt ~17: 8-granularity rounding cuts padded slots ~24 -> ~20.5.
// Pads read the zero row -> numerics identical.
__global__ __launch_bounds__(256) void
gather_bf16_kernel(const uint2* __restrict__ xb,
                   const int* __restrict__ edge_src,
                   const int* __restrict__ cursor,
                   float* __restrict__ out, int n) {
    int wave = (blockIdx.x * blockDim.x + threadIdx.x) >> 6;
    if (wave >= n) return;
    int lane = threadIdx.x & 63;
    int cnt = min(cursor[wave], CAP);                  // wave-uniform

    int s_l = (lane < cnt) ? edge_src[(size_t)wave * CAP + lane] : n;

    int sub = lane >> 4;
    int d4  = lane & 15;
    float4 acc = {0.f, 0.f, 0.f, 0.f};

    const int rounded = (cnt + 7) & ~7;
    int i = 0;
    for (; i + 32 <= rounded; i += 32) {               // 8-load MLP body
        int   s[8];
        uint2 v[8];
#pragma unroll
        for (int k = 0; k < 8; ++k)
            s[k] = __shfl(s_l, i + sub + 4 * k, 64);   // max index 32+3+28 = 63
#pragma unroll
        for (int k = 0; k < 8; ++k)
            v[k] = xb[(size_t)s[k] * 16 + d4];
#pragma unroll
        for (int k = 0; k < 8; ++k) {
            acc.x += __uint_as_float(v[k].x << 16);
            acc.y += __uint_as_float(v[k].x & 0xffff0000u);
            acc.z += __uint_as_float(v[k].y << 16);
            acc.w += __uint_as_float(v[k].y & 0xffff0000u);
        }
    }
    if (i + 16 <= rounded) {                           // 16-slot tail
        int   s[4];
        uint2 v[4];
#pragma unroll
        for (int k = 0; k < 4; ++k)
            s[k] = __shfl(s_l, i + sub + 4 * k, 64);   // max index 48+3+12 = 63
#pragma unroll
        for (int k = 0; k < 4; ++k)
            v[k] = xb[(size_t)s[k] * 16 + d4];
#pragma unroll
        for (int k = 0; k < 4; ++k) {
            acc.x += __uint_as_float(v[k].x << 16);
            acc.y += __uint_as_float(v[k].x & 0xffff0000u);
            acc.z += __uint_as_float(v[k].y << 16);
            acc.w += __uint_as_float(v[k].y & 0xffff0000u);
        }
        i += 16;
    }
    if (i < rounded) {                                 // 8-slot tail
        int   s[2];
        uint2 v[2];
#pragma unroll
        for (int k = 0; k < 2; ++k)
            s[k] = __shfl(s_l, i + sub + 4 * k, 64);   // max index 56+3+4 = 63
#pragma unroll
        for (int k = 0; k < 2; ++k)
            v[k] = xb[(size_t)s[k] * 16 + d4];
#pragma unroll
        for (int k = 0; k < 2; ++k) {
            acc.x += __uint_as_float(v[k].x << 16);
            acc.y += __uint_as_float(v[k].x & 0xffff0000u);
            acc.z += __uint_as_float(v[k].y << 16);
            acc.w += __uint_as_float(v[k].y & 0xffff0000u);
        }
    }
    for (int off = 16; off < 64; off <<= 1) {
        acc.x += __shfl_xor(acc.x, off, 64);
        acc.y += __shfl_xor(acc.y, off, 64);
        acc.z += __shfl_xor(acc.z, off, 64);
        acc.w += __shfl_xor(acc.w, off, 64);
    }
    if (sub == 0) {
        float si = rsqrtf((float)max(cnt, 1));         // rs_in
        float4 r = { acc.x * si, acc.y * si, acc.z * si, acc.w * si };
        ((float4*)out)[(size_t)wave * 16 + d4] = r;
    }
}

// ========== fallback: R8's proven single-pass fp32 path ====================
__global__ void bucket_kernel(const int* __restrict__ src, const int* __restrict__ dst,
                              int* __restrict__ cursor, int* __restrict__ deg_out,
                              int* __restrict__ edge_src, int nE) {
    int e = blockIdx.x * blockDim.x + threadIdx.x;
    if (e < nE) {
        int s = src[e];
        int d = dst[e];
        atomicAdd(&deg_out[s], 1);
        int pos = atomicAdd(&cursor[d], 1);
        if (pos < CAP) edge_src[(size_t)d * CAP + pos] = s;
    }
}

__global__ void gather_cap_kernel(const float* __restrict__ feat,
                                  const int* __restrict__ edge_src,
                                  const int* __restrict__ cursor,
                                  const int* __restrict__ deg_out,
                                  float* __restrict__ out, int n) {
    int wave = (blockIdx.x * blockDim.x + threadIdx.x) >> 6;
    if (wave >= n) return;
    int lane = threadIdx.x & 63;
    int cnt = min(cursor[wave], CAP);

    int   s_l = (lane < cnt) ? edge_src[(size_t)wave * CAP + lane] : 0;
    float w_l = (lane < cnt) ? rsqrtf((float)max(deg_out[s_l], 1)) : 0.0f;

    int sub = lane >> 4;
    int d4  = lane & 15;
    float4 a0 = {0.f,0.f,0.f,0.f}, a1 = {0.f,0.f,0.f,0.f};

    for (int i = 0; i < cnt; i += 8) {
        int   s0 = __shfl(s_l, i + sub, 64);
        float w0 = __shfl(w_l, i + sub, 64);
        int   s1 = __shfl(s_l, i + sub + 4, 64);
        float w1 = __shfl(w_l, i + sub + 4, 64);
        float4 v0 = ((const float4*)feat)[(size_t)s0 * 16 + d4];
        float4 v1 = ((const float4*)feat)[(size_t)s1 * 16 + d4];
        a0.x += w0 * v0.x; a0.y += w0 * v0.y; a0.z += w0 * v0.z; a0.w += w0 * v0.w;
        a1.x += w1 * v1.x; a1.y += w1 * v1.y; a1.z += w1 * v1.z; a1.w += w1 * v1.w;
    }
    float4 acc = { a0.x + a1.x, a0.y + a1.y, a0.z + a1.z, a0.w + a1.w };
    for (int off = 16; off < 64; off <<= 1) {
        acc.x += __shfl_xor(acc.x, off, 64);
        acc.y += __shfl_xor(acc.y, off, 64);
        acc.z += __shfl_xor(acc.z, off, 64);
        acc.w += __shfl_xor(acc.w, off, 64);
    }
    if (sub == 0) {
        float si = rsqrtf((float)max(cnt, 1));
        float4 r = { acc.x * si, acc.y * si, acc.z * si, acc.w * si };
        ((float4*)out)[(size_t)wave * 16 + d4] = r;
    }
}

// ===========================================================================

extern "C" void kernel_launch(void* const* d_in, const int* in_sizes, int n_in,
                              void* d_out, int out_size, void* d_ws, size_t ws_size,
                              hipStream_t stream) {
    const float* feat = (const float*)d_in[0];
    const int*   src  = (const int*)d_in[1];
    const int*   dst  = (const int*)d_in[2];
    float* out = (float*)d_out;
    const int nE = in_sizes[1];
    const int n  = N_NODES;

    // Fast-path layout (every section 512-B aligned; xb rows must NOT
    // straddle cache lines -- round 1's 96-mod-128 xb offset cost ~14 us):
    //   cursor[n] | dstCur[NB] srcCur[NB] | dstrec | srcrec | xb | edge_src
    // One memset covers cursor..srcCur (contiguous).
    const size_t cur_off   = 0;
    const size_t ctr_off   = (size_t)n * sizeof(int);                 // 400,000
    const size_t rec_off   = ctr_off + 2 * NB * sizeof(int);          // 401,568
    const size_t dstrec_sz = (size_t)NB * CB_CAP * sizeof(uint);
    const size_t srcrec_sz = (size_t)NB * CB_CAP * sizeof(ushort);
    const size_t xb_off    = (rec_off + dstrec_sz + srcrec_sz + 511) & ~(size_t)511;
    const size_t xb_bytes  = (size_t)(n + 1) * 16 * sizeof(uint2);    // 12,800,128
    const size_t es_off    = (xb_off + xb_bytes + 511) & ~(size_t)511;
    const size_t need_new  = es_off + (size_t)n * CAP * sizeof(int);
    const size_t need_fp   = (size_t)n * (2 + CAP) * sizeof(int);     // ~26.4 MB

    if (ws_size >= need_new) {
        char*   W        = (char*)d_ws;
        int*    cursor   = (int*)(W + cur_off);
        int*    dstCur   = (int*)(W + ctr_off);
        int*    srcCur   = dstCur + NB;
        uint*   dstrec   = (uint*)(W + rec_off);
        ushort* srcrec   = (ushort*)(W + rec_off + dstrec_sz);
        uint2*  xb       = (uint2*)(W + xb_off);
        int*    edge_src = (int*)(W + es_off);

        hipMemsetAsync(cursor, 0, rec_off, stream);   // cursor + both counters
        {
            const int chunk = EPT * PT;                       // 3584
            const int grid = (nE + chunk - 1) / chunk;        // 475 for 1.7M edges
            partition_kernel<<<grid, PT, 0, stream>>>(src, dst, dstCur, srcCur,
                                                      dstrec, srcrec, nE);
        }
        bin_kernel<<<(NBD + 1) * NB, 256, 0, stream>>>(srcrec, srcCur, dstrec, dstCur,
                                                       cursor, edge_src, feat, xb, n);
        {
            int grid = (n + 3) / 4;   // 4 waves = 4 rows per block
            gather_bf16_kernel<<<grid, 256, 0, stream>>>(xb, edge_src, cursor, out, n);
        }
    } else if (ws_size >= need_fp) {
        // R8's proven fp32 path: cursor[n] | deg_out[n] | edge_src[n*CAP]
        int* cursor   = (int*)d_ws;
        int* deg_out  = cursor + n;
        int* edge_src = deg_out + n;

        hipMemsetAsync(cursor, 0, 2 * (size_t)n * sizeof(int), stream);
        {
            int block = 256, grid = (nE + block - 1) / block;
            bucket_kernel<<<grid, block, 0, stream>>>(src, dst, cursor, deg_out, edge_src, nE);
        }
        {
            int block = 256, grid = (n + 3) / 4;
            gather_cap_kernel<<<grid, block, 0, stream>>>(feat, edge_src, cursor, deg_out, out, n);
        }
    }
}

// Round 3
// 170.135 us; speedup vs baseline: 1.2654x; 1.2654x over previous
//
#include <hip/hip_runtime.h>
#include <hip/hip_bf16.h>

#define N_NODES 100000
#define D_FEAT 64
#define CAP 64          // slots per dst node; in-deg ~ 1+Poisson(16), P(>63) ~ 1e-14
#define NB 196          // coarse buckets of 512 nodes: 196*512 = 100352 >= n
#define CB_CAP 10200    // per-coarse-bucket record capacity (mean 8673, +16 sigma)
#define PT 512          // partition threads per block
#define EPT 7           // edges register-cached per thread; chunk = EPT*PT = 3584
#define BT 512          // bin block threads

typedef unsigned int uint;
typedef unsigned short ushort;

// fp32 -> bf16 round-to-nearest-even
__device__ __forceinline__ uint f2bf(float f) {
    uint u = __float_as_uint(f);
    return (u + 0x7fffu + ((u >> 16) & 1u)) >> 16;
}

// ========== pass 1: coarse partition of edges by dst>>9 and src>>9 =========
// Single-read: each thread caches its <=EPT edges in registers (statically
// indexed under full unroll), histograms from registers, reserves one
// contiguous run per (block,bucket), then replays from registers.
__global__ __launch_bounds__(PT) void
partition_kernel(const int* __restrict__ src, const int* __restrict__ dst,
                 int* __restrict__ dstCur, int* __restrict__ srcCur,
                 uint* __restrict__ dstrec, ushort* __restrict__ srcrec,
                 int nE) {
    __shared__ int hd[NB], hs[NB], bd[NB], bs[NB];
    const int t = threadIdx.x;
    for (int i = t; i < NB; i += PT) { hd[i] = 0; hs[i] = 0; }
    __syncthreads();
    const int beg = blockIdx.x * (EPT * PT);
    int se[EPT], de[EPT];
#pragma unroll
    for (int k = 0; k < EPT; ++k) {
        int e = beg + t + k * PT;
        int s = 0, d = 0;
        if (e < nE) { s = src[e]; d = dst[e]; }   // coalesced
        se[k] = s; de[k] = d;
        if (e < nE) {
            atomicAdd(&hd[d >> 9], 1);
            atomicAdd(&hs[s >> 9], 1);
        }
    }
    __syncthreads();
    for (int i = t; i < NB; i += PT) {
        bd[i] = atomicAdd(&dstCur[i], hd[i]);
        bs[i] = atomicAdd(&srcCur[i], hs[i]);
        hd[i] = 0; hs[i] = 0;
    }
    __syncthreads();
#pragma unroll
    for (int k = 0; k < EPT; ++k) {
        int e = beg + t + k * PT;
        if (e < nE) {
            int d = de[k], s = se[k];
            int b = d >> 9;
            int p = bd[b] + atomicAdd(&hd[b], 1);
            if (p < CB_CAP)
                dstrec[(size_t)b * CB_CAP + p] = ((uint)(d & 511) << 17) | (uint)s;  // s < 2^17
            int b2 = s >> 9;
            int p2 = bs[b2] + atomicAdd(&hs[b2], 1);
            if (p2 < CB_CAP)
                srcrec[(size_t)b2 * CB_CAP + p2] = (ushort)(s & 511);
        }
    }
}

// ========== pass 2: fused bin + prescale ===================================
// Blocks 0..NB-1: fine-bin dst records -> edge_src + cursor via per-bucket
//   LDS cursors (block-local ~20cy atomics; round 2 proved global
//   atomic-with-return cursors are 2x worse: L2 same-address serialization).
// Blocks NB..2NB-1: deg_out histogram in LDS, then directly emit prescaled
//   bf16 rows xb[row] = bf16(rsqrt(deg_out)*feat[row]); deg_out never
//   touches global memory; separate prescale dispatch eliminated.
__global__ __launch_bounds__(BT) void
bin_kernel(const ushort* __restrict__ srcrec, const int* __restrict__ srcCur,
           const uint* __restrict__ dstrec, const int* __restrict__ dstCur,
           int* __restrict__ cursor, int* __restrict__ edge_src,
           const float* __restrict__ feat, uint2* __restrict__ xb, int n) {
    __shared__ int lc[512];
    const int t = threadIdx.x;
    if ((int)blockIdx.x < NB) {
        const int b = blockIdx.x;
        const int base = b << 9;
        const int nNodes = min(512, n - base);
        for (int i = t; i < 512; i += BT) lc[i] = 0;
        __syncthreads();
        int cnt = min(dstCur[b], CB_CAP);
        const uint* rec = dstrec + (size_t)b * CB_CAP;
        for (int i = t; i < cnt; i += BT) {
            uint r = rec[i];
            int dl = r >> 17;
            int s  = r & 0x1FFFF;
            int p = atomicAdd(&lc[dl], 1);
            if (p < CAP) edge_src[(size_t)(base + dl) * CAP + p] = s;  // 128 KB L2-local
        }
        __syncthreads();
        for (int i = t; i < nNodes; i += BT) cursor[base + i] = lc[i];
    } else {
        const int b = blockIdx.x - NB;
        const int base = b << 9;
        for (int i = t; i < 512; i += BT) lc[i] = 0;
        __syncthreads();
        int cnt = min(srcCur[b], CB_CAP);
        const ushort* rec = srcrec + (size_t)b * CB_CAP;
        for (int i = t; i < cnt; i += BT) atomicAdd(&lc[rec[i]], 1);
        __syncthreads();
        // prescale this bucket's rows; include pad row n (zeros) when in range.
        const int rows = min(512, n + 1 - base);
        const int d4 = t & 15;
        for (int r = t >> 4; r < rows; r += BT / 16) {   // 32 rows/iter, coalesced 1KB/wave
            const int row = base + r;
            uint2 o;
            if (row == n) {
                o.x = 0u; o.y = 0u;
            } else {
                float w = rsqrtf((float)max(lc[r], 1));
                float4 v = ((const float4*)feat)[(size_t)row * 16 + d4];
                o.x = f2bf(w * v.x) | (f2bf(w * v.y) << 16);
                o.y = f2bf(w * v.z) | (f2bf(w * v.w) << 16);
            }
            xb[(size_t)row * 16 + d4] = o;
        }
    }
}

// ========== pass 3: gather (body 32 / tail 16 / tail 8) ====================
// One wave per dst row; WAVE-UNIFORM loop (shfl source lanes must stay active).
// Avg cnt ~17: 8-granularity rounding cuts padded slots ~24 -> ~20.5.
// Pads read the zero row -> numerics identical.
__global__ __launch_bounds__(256) void
gather_bf16_kernel(const uint2* __restrict__ xb,
                   const int* __restrict__ edge_src,
                   const int* __restrict__ cursor,
                   float* __restrict__ out, int n) {
    int wave = (blockIdx.x * blockDim.x + threadIdx.x) >> 6;
    if (wave >= n) return;
    int lane = threadIdx.x & 63;
    int cnt = min(cursor[wave], CAP);                  // wave-uniform

    int s_l = (lane < cnt) ? edge_src[(size_t)wave * CAP + lane] : n;

    int sub = lane >> 4;
    int d4  = lane & 15;
    float4 acc = {0.f, 0.f, 0.f, 0.f};

    const int rounded = (cnt + 7) & ~7;
    int i = 0;
    for (; i + 32 <= rounded; i += 32) {               // 8-load MLP body
        int   s[8];
        uint2 v[8];
#pragma unroll
        for (int k = 0; k < 8; ++k)
            s[k] = __shfl(s_l, i + sub + 4 * k, 64);   // max index 32+3+28 = 63
#pragma unroll
        for (int k = 0; k < 8; ++k)
            v[k] = xb[(size_t)s[k] * 16 + d4];
#pragma unroll
        for (int k = 0; k < 8; ++k) {
            acc.x += __uint_as_float(v[k].x << 16);
            acc.y += __uint_as_float(v[k].x & 0xffff0000u);
            acc.z += __uint_as_float(v[k].y << 16);
            acc.w += __uint_as_float(v[k].y & 0xffff0000u);
        }
    }
    if (i + 16 <= rounded) {                           // 16-slot tail
        int   s[4];
        uint2 v[4];
#pragma unroll
        for (int k = 0; k < 4; ++k)
            s[k] = __shfl(s_l, i + sub + 4 * k, 64);   // max index 48+3+12 = 63
#pragma unroll
        for (int k = 0; k < 4; ++k)
            v[k] = xb[(size_t)s[k] * 16 + d4];
#pragma unroll
        for (int k = 0; k < 4; ++k) {
            acc.x += __uint_as_float(v[k].x << 16);
            acc.y += __uint_as_float(v[k].x & 0xffff0000u);
            acc.z += __uint_as_float(v[k].y << 16);
            acc.w += __uint_as_float(v[k].y & 0xffff0000u);
        }
        i += 16;
    }
    if (i < rounded) {                                 // 8-slot tail
        int   s[2];
        uint2 v[2];
#pragma unroll
        for (int k = 0; k < 2; ++k)
            s[k] = __shfl(s_l, i + sub + 4 * k, 64);   // max index 56+3+4 = 63
#pragma unroll
        for (int k = 0; k < 2; ++k)
            v[k] = xb[(size_t)s[k] * 16 + d4];
#pragma unroll
        for (int k = 0; k < 2; ++k) {
            acc.x += __uint_as_float(v[k].x << 16);
            acc.y += __uint_as_float(v[k].x & 0xffff0000u);
            acc.z += __uint_as_float(v[k].y << 16);
            acc.w += __uint_as_float(v[k].y & 0xffff0000u);
        }
    }
    for (int off = 16; off < 64; off <<= 1) {
        acc.x += __shfl_xor(acc.x, off, 64);
        acc.y += __shfl_xor(acc.y, off, 64);
        acc.z += __shfl_xor(acc.z, off, 64);
        acc.w += __shfl_xor(acc.w, off, 64);
    }
    if (sub == 0) {
        float si = rsqrtf((float)max(cnt, 1));         // rs_in
        float4 r = { acc.x * si, acc.y * si, acc.z * si, acc.w * si };
        ((float4*)out)[(size_t)wave * 16 + d4] = r;
    }
}

// ========== fallback: R8's proven single-pass fp32 path ====================
__global__ void bucket_kernel(const int* __restrict__ src, const int* __restrict__ dst,
                              int* __restrict__ cursor, int* __restrict__ deg_out,
                              int* __restrict__ edge_src, int nE) {
    int e = blockIdx.x * blockDim.x + threadIdx.x;
    if (e < nE) {
        int s = src[e];
        int d = dst[e];
        atomicAdd(&deg_out[s], 1);
        int pos = atomicAdd(&cursor[d], 1);
        if (pos < CAP) edge_src[(size_t)d * CAP + pos] = s;
    }
}

__global__ void gather_cap_kernel(const float* __restrict__ feat,
                                  const int* __restrict__ edge_src,
                                  const int* __restrict__ cursor,
                                  const int* __restrict__ deg_out,
                                  float* __restrict__ out, int n) {
    int wave = (blockIdx.x * blockDim.x + threadIdx.x) >> 6;
    if (wave >= n) return;
    int lane = threadIdx.x & 63;
    int cnt = min(cursor[wave], CAP);

    int   s_l = (lane < cnt) ? edge_src[(size_t)wave * CAP + lane] : 0;
    float w_l = (lane < cnt) ? rsqrtf((float)max(deg_out[s_l], 1)) : 0.0f;

    int sub = lane >> 4;
    int d4  = lane & 15;
    float4 a0 = {0.f,0.f,0.f,0.f}, a1 = {0.f,0.f,0.f,0.f};

    for (int i = 0; i < cnt; i += 8) {
        int   s0 = __shfl(s_l, i + sub, 64);
        float w0 = __shfl(w_l, i + sub, 64);
        int   s1 = __shfl(s_l, i + sub + 4, 64);
        float w1 = __shfl(w_l, i + sub + 4, 64);
        float4 v0 = ((const float4*)feat)[(size_t)s0 * 16 + d4];
        float4 v1 = ((const float4*)feat)[(size_t)s1 * 16 + d4];
        a0.x += w0 * v0.x; a0.y += w0 * v0.y; a0.z += w0 * v0.z; a0.w += w0 * v0.w;
        a1.x += w1 * v1.x; a1.y += w1 * v1.y; a1.z += w1 * v1.z; a1.w += w1 * v1.w;
    }
    float4 acc = { a0.x + a1.x, a0.y + a1.y, a0.z + a1.z, a0.w + a1.w };
    for (int off = 16; off < 64; off <<= 1) {
        acc.x += __shfl_xor(acc.x, off, 64);
        acc.y += __shfl_xor(acc.y, off, 64);
        acc.z += __shfl_xor(acc.z, off, 64);
        acc.w += __shfl_xor(acc.w, off, 64);
    }
    if (sub == 0) {
        float si = rsqrtf((float)max(cnt, 1));
        float4 r = { acc.x * si, acc.y * si, acc.z * si, acc.w * si };
        ((float4*)out)[(size_t)wave * 16 + d4] = r;
    }
}

// ===========================================================================

extern "C" void kernel_launch(void* const* d_in, const int* in_sizes, int n_in,
                              void* d_out, int out_size, void* d_ws, size_t ws_size,
                              hipStream_t stream) {
    const float* feat = (const float*)d_in[0];
    const int*   src  = (const int*)d_in[1];
    const int*   dst  = (const int*)d_in[2];
    float* out = (float*)d_out;
    const int nE = in_sizes[1];
    const int n  = N_NODES;

    // Fast-path layout (every section 512-B aligned; xb rows must NOT
    // straddle cache lines -- round 1's 96-mod-128 xb offset cost ~14 us):
    //   cursor[n] | dstCur[NB] srcCur[NB] | dstrec | srcrec | xb | edge_src
    const size_t cur_off   = 0;
    const size_t ctr_off   = (size_t)n * sizeof(int);                 // 400,000
    const size_t rec_off   = ctr_off + 2 * NB * sizeof(int);          // 401,568
    const size_t dstrec_sz = (size_t)NB * CB_CAP * sizeof(uint);
    const size_t srcrec_sz = (size_t)NB * CB_CAP * sizeof(ushort);
    const size_t xb_off    = (rec_off + dstrec_sz + srcrec_sz + 511) & ~(size_t)511;
    const size_t xb_bytes  = (size_t)(n + 1) * 16 * sizeof(uint2);    // 12,800,128
    const size_t es_off    = (xb_off + xb_bytes + 511) & ~(size_t)511;
    const size_t need_new  = es_off + (size_t)n * CAP * sizeof(int);
    const size_t need_fp   = (size_t)n * (2 + CAP) * sizeof(int);     // ~26.4 MB

    if (ws_size >= need_new) {
        char*   W        = (char*)d_ws;
        int*    cursor   = (int*)(W + cur_off);
        int*    dstCur   = (int*)(W + ctr_off);
        int*    srcCur   = dstCur + NB;
        uint*   dstrec   = (uint*)(W + rec_off);
        ushort* srcrec   = (ushort*)(W + rec_off + dstrec_sz);
        uint2*  xb       = (uint2*)(W + xb_off);
        int*    edge_src = (int*)(W + es_off);

        // bin writes cursor[] directly from LDS -> only counters need zeroing.
        hipMemsetAsync(dstCur, 0, 2 * NB * sizeof(int), stream);
        {
            const int chunk = EPT * PT;                       // 3584
            const int grid = (nE + chunk - 1) / chunk;        // 475 for 1.7M edges
            partition_kernel<<<grid, PT, 0, stream>>>(src, dst, dstCur, srcCur,
                                                      dstrec, srcrec, nE);
        }
        bin_kernel<<<2 * NB, BT, 0, stream>>>(srcrec, srcCur, dstrec, dstCur,
                                              cursor, edge_src, feat, xb, n);
        {
            int grid = (n + 3) / 4;   // 4 waves = 4 rows per block
            gather_bf16_kernel<<<grid, 256, 0, stream>>>(xb, edge_src, cursor, out, n);
        }
    } else if (ws_size >= need_fp) {
        // R8's proven fp32 path: cursor[n] | deg_out[n] | edge_src[n*CAP]
        int* cursor   = (int*)d_ws;
        int* deg_out  = cursor + n;
        int* edge_src = deg_out + n;

        hipMemsetAsync(cursor, 0, 2 * (size_t)n * sizeof(int), stream);
        {
            int block = 256, grid = (nE + block - 1) / block;
            bucket_kernel<<<grid, block, 0, stream>>>(src, dst, cursor, deg_out, edge_src, nE);
        }
        {
            int block = 256, grid = (n + 3) / 4;
            gather_cap_kernel<<<grid, block, 0, stream>>>(feat, edge_src, cursor, deg_out, out, n);
        }
    }
}